// Round 1
// baseline (278.583 us; speedup 1.0000x reference)
//
#include <hip/hip_runtime.h>
#include <hip/hip_bf16.h>

typedef __attribute__((ext_vector_type(4))) float float4v;
typedef __attribute__((ext_vector_type(8))) __bf16 bf16x8;
typedef __attribute__((ext_vector_type(4))) unsigned short ushort4v;

#define MFMA16(a, b, c) __builtin_amdgcn_mfma_f32_16x16x32_bf16(a, b, c, 0, 0, 0)

__device__ __forceinline__ unsigned short f2bf(float f) {
    return __builtin_bit_cast(unsigned short, (__bf16)f);
}

// 2^x via native v_exp_f32 (args bounded above by ~13; may be -1e18 -> 0)
__device__ __forceinline__ float fast_exp2(float x) {
#if __has_builtin(__builtin_amdgcn_exp2f)
    return __builtin_amdgcn_exp2f(x);
#else
    return exp2f(x);
#endif
}

// async global->LDS, 16B per lane; lds dest must be wave-uniform base + lane*16
__device__ __forceinline__ void gl_lds16(const unsigned short* g, unsigned short* l) {
    __builtin_amdgcn_global_load_lds(
        (const __attribute__((address_space(1))) void*)g,
        (__attribute__((address_space(3))) void*)l, 16, 0, 0);
}

// ---------------------------------------------------------------------------
// fp32 -> bf16 convert, 7 segments in one launch
// ---------------------------------------------------------------------------
struct CvtSeg { const float* s; unsigned short* d; int n; };
struct Cvt7 { CvtSeg seg[7]; };

__global__ __launch_bounds__(256) void cvt_kernel(Cvt7 a) {
    const CvtSeg c = a.seg[blockIdx.y];
    const int stride = gridDim.x * 256 * 4;
    for (int i = (blockIdx.x * 256 + threadIdx.x) * 4; i < c.n; i += stride) {
        float4v v = *(const float4v*)(c.s + i);
        ushort4v u;
        u.x = f2bf(v.x); u.y = f2bf(v.y); u.z = f2bf(v.z); u.w = f2bf(v.w);
        *(ushort4v*)(c.d + i) = u;
    }
}

// ---------------------------------------------------------------------------
// 128x128-tile GEMM (QKV projections): C = (A W^T + bias) * scale, bf16 out.
// ---------------------------------------------------------------------------
__device__ __forceinline__ void gemm128_body(const unsigned short* __restrict__ A,
                                             const unsigned short* __restrict__ W,
                                             const float* __restrict__ bias,
                                             unsigned short* __restrict__ Cout,
                                             int N, int K, float scale,
                                             unsigned short* As, unsigned short* Ws) {
    const int t = threadIdx.x;
    const int w = t >> 6, lane = t & 63;
    const int quad = lane >> 4, l16 = lane & 15;
    const int m0 = blockIdx.x * 128, n0 = blockIdx.y * 128;
    const int wm = (w >> 1) * 64, wn = (w & 1) * 64;

    float4v acc[4][4];
    for (int i = 0; i < 4; ++i)
        for (int j = 0; j < 4; ++j) acc[i][j] = float4v{0.f, 0.f, 0.f, 0.f};

    const int srow = lane >> 3;
    const int scol = (lane & 7) * 8;

    for (int k0 = 0; k0 < K; k0 += 64) {
        __syncthreads();
        for (int i = 0; i < 4; ++i) {
            const int c = w * 4 + i;
            gl_lds16(A + (size_t)(m0 + c * 8 + srow) * K + k0 + scol,
                     &As[c * 512 + lane * 8]);
            gl_lds16(W + (size_t)(n0 + c * 8 + srow) * K + k0 + scol,
                     &Ws[c * 512 + lane * 8]);
        }
        __syncthreads();
        for (int ks = 0; ks < 2; ++ks) {
            bf16x8 af[4], wf[4];
            for (int i = 0; i < 4; ++i)
                af[i] = *(const bf16x8*)&As[(wm + i * 16 + l16) * 64 + ks * 32 + quad * 8];
            for (int i = 0; i < 4; ++i)
                wf[i] = *(const bf16x8*)&Ws[(wn + i * 16 + l16) * 64 + ks * 32 + quad * 8];
            for (int mi = 0; mi < 4; ++mi)
                for (int ni = 0; ni < 4; ++ni)
                    acc[mi][ni] = MFMA16(af[mi], wf[ni], acc[mi][ni]);
        }
    }

    for (int mi = 0; mi < 4; ++mi)
        for (int ni = 0; ni < 4; ++ni) {
            const int col = n0 + wn + ni * 16 + l16;
            const float bv = bias[col];
            for (int reg = 0; reg < 4; ++reg) {
                const int row = m0 + wm + mi * 16 + quad * 4 + reg;
                Cout[(size_t)row * N + col] = f2bf((acc[mi][ni][reg] + bv) * scale);
            }
        }
}

__global__ __launch_bounds__(256) void gemm_qkv_kernel(
    const unsigned short* qa, const unsigned short* ka, const unsigned short* va,
    const unsigned short* Wqb, const unsigned short* Wkb, const unsigned short* Wvb,
    const float* bq, const float* bk, const float* bv,
    unsigned short* Qb, unsigned short* Kb, unsigned short* Vb, float qscale) {
    __shared__ unsigned short As[128 * 64];
    __shared__ unsigned short Ws[128 * 64];
    const int z = blockIdx.z;
    const unsigned short* A = z == 0 ? qa : (z == 1 ? ka : va);
    const unsigned short* W = z == 0 ? Wqb : (z == 1 ? Wkb : Wvb);
    const float* bias = z == 0 ? bq : (z == 1 ? bk : bv);
    unsigned short* C = z == 0 ? Qb : (z == 1 ? Kb : Vb);
    gemm128_body(A, W, bias, C, 1024, 1024, z == 0 ? qscale : 1.0f, As, Ws);
}

// ---------------------------------------------------------------------------
// 64x128-tile GEMM (output projection, fp32 out). 512 blocks = 2 blocks/CU.
// ---------------------------------------------------------------------------
__global__ __launch_bounds__(256) void gemm_out_kernel(const unsigned short* __restrict__ A,
                                                       const unsigned short* __restrict__ W,
                                                       const float* __restrict__ bias,
                                                       float* __restrict__ Cout) {
    __shared__ unsigned short As[64 * 64];
    __shared__ unsigned short Ws[128 * 64];
    const int N = 1024, K = 1024;
    const int t = threadIdx.x;
    const int w = t >> 6, lane = t & 63;
    const int quad = lane >> 4, l16 = lane & 15;
    const int m0 = blockIdx.x * 64, n0 = blockIdx.y * 128;
    const int wm = (w & 1) * 32, wn = (w >> 1) * 64;

    float4v acc[2][4];
    for (int i = 0; i < 2; ++i)
        for (int j = 0; j < 4; ++j) acc[i][j] = float4v{0.f, 0.f, 0.f, 0.f};

    const int srow = lane >> 3;
    const int scol = (lane & 7) * 8;

    for (int k0 = 0; k0 < K; k0 += 64) {
        __syncthreads();
        for (int i = 0; i < 2; ++i) {
            const int c = w * 2 + i;
            gl_lds16(A + (size_t)(m0 + c * 8 + srow) * K + k0 + scol,
                     &As[c * 512 + lane * 8]);
        }
        for (int i = 0; i < 4; ++i) {
            const int c = w * 4 + i;
            gl_lds16(W + (size_t)(n0 + c * 8 + srow) * K + k0 + scol,
                     &Ws[c * 512 + lane * 8]);
        }
        __syncthreads();
        for (int ks = 0; ks < 2; ++ks) {
            bf16x8 af[2], wf[4];
            for (int i = 0; i < 2; ++i)
                af[i] = *(const bf16x8*)&As[(wm + i * 16 + l16) * 64 + ks * 32 + quad * 8];
            for (int i = 0; i < 4; ++i)
                wf[i] = *(const bf16x8*)&Ws[(wn + i * 16 + l16) * 64 + ks * 32 + quad * 8];
            for (int mi = 0; mi < 2; ++mi)
                for (int ni = 0; ni < 4; ++ni)
                    acc[mi][ni] = MFMA16(af[mi], wf[ni], acc[mi][ni]);
        }
    }

    for (int mi = 0; mi < 2; ++mi)
        for (int ni = 0; ni < 4; ++ni) {
            const int col = n0 + wn + ni * 16 + l16;
            const float bv = bias[col];
            for (int reg = 0; reg < 4; ++reg) {
                const int row = m0 + wm + mi * 16 + quad * 4 + reg;
                Cout[(size_t)row * N + col] = acc[mi][ni][reg] + bv;
            }
        }
}

// ---------------------------------------------------------------------------
// Flash attention, S^T formulation, 128 q-rows/block (32 q per wave).
// SPLIT-K variant: grid 1024 = (half, qt, bh); each block does 1024 keys and
// writes unnormalized f32 partial O + partial row-sum l to workspace.
// No online-max -> the key split is exact; merge kernel does (O0+O1)/(l0+l1).
// 4 blocks/CU (vs 2) doubles resident waves: LDS/VALU/MFMA phases overlap.
// ---------------------------------------------------------------------------
__global__ __launch_bounds__(256, 4) void attn_split_kernel(
        const unsigned short* __restrict__ Q,
        const unsigned short* __restrict__ Kg,
        const unsigned short* __restrict__ Vg,
        const unsigned char* __restrict__ mask,
        float* __restrict__ Opart, float* __restrict__ Lpart) {
    const int bid = blockIdx.x;
    const int bh = bid & 31;          // fastest -> same-XCD blocks share (b,h) K/V
    const int qt = (bid >> 5) & 15;   // 0..15 (128-row q tile)
    const int half = bid >> 9;        // 0..1 (key half)
    const int b = bh >> 4, h = bh & 15;
    const int t = threadIdx.x, w = t >> 6, lane = t & 63;
    const int quad = lane >> 4, l16 = lane & 15;

    __shared__ unsigned short Pt[128][72];  // Q at start; then P in A-layout [q][key]
    __shared__ unsigned short Ks[64][72];
    __shared__ unsigned short Vt[64][72];   // transposed V: Vt[d][k]

    const unsigned short* Qp = Q + ((size_t)(b * 2048 + qt * 128)) * 1024 + h * 64;
    const unsigned short* Kp = Kg + ((size_t)b * 2048) * 1024 + h * 64;
    const unsigned short* Vp = Vg + ((size_t)b * 2048) * 1024 + h * 64;
    const unsigned char* Mp = mask + (size_t)(b * 2048 + qt * 128) * 2048;

    for (int p = 0; p < 4; ++p) {  // Q tile 128x64 -> Pt
        const int idx = t + p * 256;
        const int r = idx >> 3, c8 = (idx & 7) * 8;
        *(uint4*)&Pt[r][c8] = *(const uint4*)(Qp + (size_t)r * 1024 + c8);
    }
    __syncthreads();
    // qf[c] = B-operand fragment for q-group c (q = w*32 + c*16 + l16)
    bf16x8 qf[2][2];
    for (int c = 0; c < 2; ++c)
        for (int ks = 0; ks < 2; ++ks)
            qf[c][ks] = *(const bf16x8*)&Pt[w * 32 + c * 16 + l16][ks * 32 + quad * 8];

    float4v o[2][4];  // [q-chunk][d-tile]
    for (int c = 0; c < 2; ++c)
        for (int i = 0; i < 4; ++i) o[c][i] = float4v{0.f, 0.f, 0.f, 0.f};
    float l_acc[2] = {0.f, 0.f};  // per-lane partial row-sum for q-group c

    const int sr = t >> 3, sc8 = (t & 7) * 8;          // K staging map
    const int vkk = (t & 31) * 2, vd0 = (t >> 5) * 8;  // V staging map
    const int mrow = w * 32 + (lane >> 1);             // mask probe: 32 rows x 64 B
    const int mc0 = (lane & 1) * 32;

    const int kbase = half << 10;      // 0 or 1024
    const int kend = kbase + 1024;

    uint4 kreg0, kreg1, vreg0, vreg1, mreg0, mreg1;
    {
        kreg0 = *(const uint4*)(Kp + (size_t)(kbase + sr) * 1024 + sc8);
        kreg1 = *(const uint4*)(Kp + (size_t)(kbase + sr + 32) * 1024 + sc8);
        vreg0 = *(const uint4*)(Vp + (size_t)(kbase + vkk) * 1024 + vd0);
        vreg1 = *(const uint4*)(Vp + (size_t)(kbase + vkk + 1) * 1024 + vd0);
        mreg0 = *(const uint4*)(Mp + (size_t)mrow * 2048 + kbase + mc0);
        mreg1 = *(const uint4*)(Mp + (size_t)mrow * 2048 + kbase + mc0 + 16);
    }

    for (int kc = kbase; kc < kend; kc += 64) {
        __syncthreads();  // prev iter's Ks/Vt readers done
        *(uint4*)&Ks[sr][sc8] = kreg0;
        *(uint4*)&Ks[sr + 32][sc8] = kreg1;
        {
            const unsigned short* pa = (const unsigned short*)&vreg0;
            const unsigned short* pb = (const unsigned short*)&vreg1;
            for (int j = 0; j < 8; ++j)
                *(unsigned int*)&Vt[vd0 + j][vkk] =
                    (unsigned int)pa[j] | ((unsigned int)pb[j] << 16);
        }
        const unsigned int mor = mreg0.x | mreg0.y | mreg0.z | mreg0.w |
                                 mreg1.x | mreg1.y | mreg1.z | mreg1.w;
        const bool anymask = __any(mor != 0);
        __syncthreads();  // staged data visible

        const int kn = kc + 64;
        if (kn < kend) {  // prefetch next tile
            kreg0 = *(const uint4*)(Kp + (size_t)(kn + sr) * 1024 + sc8);
            kreg1 = *(const uint4*)(Kp + (size_t)(kn + sr + 32) * 1024 + sc8);
            vreg0 = *(const uint4*)(Vp + (size_t)(kn + vkk) * 1024 + vd0);
            vreg1 = *(const uint4*)(Vp + (size_t)(kn + vkk + 1) * 1024 + vd0);
            mreg0 = *(const uint4*)(Mp + (size_t)mrow * 2048 + kn + mc0);
            mreg1 = *(const uint4*)(Mp + (size_t)mrow * 2048 + kn + mc0 + 16);
        }

        // S^T = K Q^T for both q-groups; each kf read feeds 2 MFMAs
        float4v s0[4], s1[4];
        for (int nt = 0; nt < 4; ++nt) {
            const float4v z4 = float4v{0.f, 0.f, 0.f, 0.f};
            bf16x8 kf = *(const bf16x8*)&Ks[nt * 16 + l16][quad * 8];
            s0[nt] = MFMA16(kf, qf[0][0], z4);
            s1[nt] = MFMA16(kf, qf[1][0], z4);
            kf = *(const bf16x8*)&Ks[nt * 16 + l16][32 + quad * 8];
            s0[nt] = MFMA16(kf, qf[0][1], s0[nt]);
            s1[nt] = MFMA16(kf, qf[1][1], s1[nt]);
        }

        // exp2 + pack 4 consecutive keys -> one b64 store in A-layout
        for (int c = 0; c < 2; ++c) {
            float4v* s = c ? s1 : s0;
            const int qrow = w * 32 + c * 16 + l16;  // wave-private Pt row
            float lc = l_acc[c];
            for (int nt = 0; nt < 4; ++nt) {
                float p0 = s[nt][0], p1 = s[nt][1], p2 = s[nt][2], p3 = s[nt][3];
                if (anymask) {  // rare slow path: scalar byte re-read
                    const unsigned char* mr =
                        Mp + (size_t)qrow * 2048 + kc + nt * 16 + quad * 4;
                    if (mr[0]) p0 = -1e18f;
                    if (mr[1]) p1 = -1e18f;
                    if (mr[2]) p2 = -1e18f;
                    if (mr[3]) p3 = -1e18f;
                }
                const float e0 = fast_exp2(p0), e1 = fast_exp2(p1);
                const float e2 = fast_exp2(p2), e3 = fast_exp2(p3);
                lc += (e0 + e1) + (e2 + e3);
                uint2 u;
                u.x = (unsigned int)f2bf(e0) | ((unsigned int)f2bf(e1) << 16);
                u.y = (unsigned int)f2bf(e2) | ((unsigned int)f2bf(e3) << 16);
                *(uint2*)&Pt[qrow][nt * 16 + quad * 4] = u;
            }
            l_acc[c] = lc;
        }

        // O += P V ; each vf read feeds 2 MFMAs (both q-chunks)
        for (int ks = 0; ks < 2; ++ks) {
            bf16x8 pf0 = *(const bf16x8*)&Pt[w * 32 + l16][ks * 32 + quad * 8];
            bf16x8 pf1 = *(const bf16x8*)&Pt[w * 32 + 16 + l16][ks * 32 + quad * 8];
            for (int dt = 0; dt < 4; ++dt) {
                bf16x8 vf = *(const bf16x8*)&Vt[dt * 16 + l16][ks * 32 + quad * 8];
                o[0][dt] = MFMA16(pf0, vf, o[0][dt]);
                o[1][dt] = MFMA16(pf1, vf, o[1][dt]);
            }
        }
    }

    // reduce l over quads (uniform across quads after xor 16/32), per q-group
    float lfull[2];
    for (int c = 0; c < 2; ++c) {
        float l = l_acc[c];
        l += __shfl_xor(l, 16);
        l += __shfl_xor(l, 32);
        lfull[c] = l;
    }

    // write unnormalized partial O (f32) + partial l
    const int pb = bid & 511;  // (qt*32 + bh)
    float* Op = Opart + (size_t)half * (512 * 8192) + (size_t)pb * 8192;
    float* Lp = Lpart + (size_t)half * (512 * 128) + (size_t)pb * 128;
    for (int c = 0; c < 2; ++c) {
        if (quad == 0) Lp[w * 32 + c * 16 + l16] = lfull[c];
        for (int dt = 0; dt < 4; ++dt) {
            const int dcol = dt * 16 + l16;
            for (int reg = 0; reg < 4; ++reg) {
                const int ql = w * 32 + c * 16 + quad * 4 + reg;
                Op[ql * 64 + dcol] = o[c][dt][reg];
            }
        }
    }
}

// merge: ctx = (O0 + O1) / (l0 + l1), bf16 out.  512 blocks x 256 threads.
__global__ __launch_bounds__(256) void attn_merge_kernel(
        const float* __restrict__ Opart, const float* __restrict__ Lpart,
        unsigned short* __restrict__ Ctx) {
    const int pb = blockIdx.x;  // qt*32 + bh
    const int bh = pb & 31, qt = pb >> 5;
    const int b = bh >> 4, h = bh & 15;
    const int t = threadIdx.x;
    __shared__ float invl[128];
    if (t < 128) {
        const float l0 = Lpart[(size_t)pb * 128 + t];
        const float l1 = Lpart[(size_t)(512 * 128) + (size_t)pb * 128 + t];
        invl[t] = 1.0f / (l0 + l1);
    }
    __syncthreads();
    const float* O0 = Opart + (size_t)pb * 8192;
    const float* O1 = Opart + (size_t)(512 * 8192) + (size_t)pb * 8192;
    for (int i = 0; i < 8; ++i) {
        const int idx4 = t + i * 256;       // float4 index, 0..2047
        const int ql = idx4 >> 4;
        const int d4 = (idx4 & 15) * 4;
        const float4v a = *(const float4v*)(O0 + (size_t)idx4 * 4);
        const float4v c = *(const float4v*)(O1 + (size_t)idx4 * 4);
        const float s = invl[ql];
        ushort4v u;
        u.x = f2bf((a.x + c.x) * s);
        u.y = f2bf((a.y + c.y) * s);
        u.z = f2bf((a.z + c.z) * s);
        u.w = f2bf((a.w + c.w) * s);
        *(ushort4v*)(Ctx + ((size_t)(b * 2048 + qt * 128 + ql)) * 1024 + h * 64 + d4) = u;
    }
}

// ---------------------------------------------------------------------------
// Fallback (original) attention: full 2048 keys per block, grid 512.
// Used only if the workspace is too small for f32 split-K partials.
// ---------------------------------------------------------------------------
__global__ __launch_bounds__(256) void attn_kernel(const unsigned short* __restrict__ Q,
                                                   const unsigned short* __restrict__ Kg,
                                                   const unsigned short* __restrict__ Vg,
                                                   const unsigned char* __restrict__ mask,
                                                   unsigned short* __restrict__ Ctx) {
    const int bid = blockIdx.x;
    const int bh = bid & 31;
    const int qt = bid >> 5;
    const int b = bh >> 4, h = bh & 15;
    const int t = threadIdx.x, w = t >> 6, lane = t & 63;
    const int quad = lane >> 4, l16 = lane & 15;

    __shared__ unsigned short Pt[128][72];
    __shared__ unsigned short Ks[64][72];
    __shared__ unsigned short Vt[64][72];

    const unsigned short* Qp = Q + ((size_t)(b * 2048 + qt * 128)) * 1024 + h * 64;
    const unsigned short* Kp = Kg + ((size_t)b * 2048) * 1024 + h * 64;
    const unsigned short* Vp = Vg + ((size_t)b * 2048) * 1024 + h * 64;
    const unsigned char* Mp = mask + (size_t)(b * 2048 + qt * 128) * 2048;

    for (int p = 0; p < 4; ++p) {
        const int idx = t + p * 256;
        const int r = idx >> 3, c8 = (idx & 7) * 8;
        *(uint4*)&Pt[r][c8] = *(const uint4*)(Qp + (size_t)r * 1024 + c8);
    }
    __syncthreads();
    bf16x8 qf[2][2];
    for (int c = 0; c < 2; ++c)
        for (int ks = 0; ks < 2; ++ks)
            qf[c][ks] = *(const bf16x8*)&Pt[w * 32 + c * 16 + l16][ks * 32 + quad * 8];

    float4v o[2][4];
    for (int c = 0; c < 2; ++c)
        for (int i = 0; i < 4; ++i) o[c][i] = float4v{0.f, 0.f, 0.f, 0.f};
    float l_acc[2] = {0.f, 0.f};

    const int sr = t >> 3, sc8 = (t & 7) * 8;
    const int vkk = (t & 31) * 2, vd0 = (t >> 5) * 8;
    const int mrow = w * 32 + (lane >> 1);
    const int mc0 = (lane & 1) * 32;

    uint4 kreg0, kreg1, vreg0, vreg1, mreg0, mreg1;
    {
        kreg0 = *(const uint4*)(Kp + (size_t)sr * 1024 + sc8);
        kreg1 = *(const uint4*)(Kp + (size_t)(sr + 32) * 1024 + sc8);
        vreg0 = *(const uint4*)(Vp + (size_t)vkk * 1024 + vd0);
        vreg1 = *(const uint4*)(Vp + (size_t)(vkk + 1) * 1024 + vd0);
        mreg0 = *(const uint4*)(Mp + (size_t)mrow * 2048 + mc0);
        mreg1 = *(const uint4*)(Mp + (size_t)mrow * 2048 + mc0 + 16);
    }

    for (int kc = 0; kc < 2048; kc += 64) {
        __syncthreads();
        *(uint4*)&Ks[sr][sc8] = kreg0;
        *(uint4*)&Ks[sr + 32][sc8] = kreg1;
        {
            const unsigned short* pa = (const unsigned short*)&vreg0;
            const unsigned short* pb = (const unsigned short*)&vreg1;
            for (int j = 0; j < 8; ++j)
                *(unsigned int*)&Vt[vd0 + j][vkk] =
                    (unsigned int)pa[j] | ((unsigned int)pb[j] << 16);
        }
        const unsigned int mor = mreg0.x | mreg0.y | mreg0.z | mreg0.w |
                                 mreg1.x | mreg1.y | mreg1.z | mreg1.w;
        const bool anymask = __any(mor != 0);
        __syncthreads();

        const int kn = kc + 64;
        if (kn < 2048) {
            kreg0 = *(const uint4*)(Kp + (size_t)(kn + sr) * 1024 + sc8);
            kreg1 = *(const uint4*)(Kp + (size_t)(kn + sr + 32) * 1024 + sc8);
            vreg0 = *(const uint4*)(Vp + (size_t)(kn + vkk) * 1024 + vd0);
            vreg1 = *(const uint4*)(Vp + (size_t)(kn + vkk + 1) * 1024 + vd0);
            mreg0 = *(const uint4*)(Mp + (size_t)mrow * 2048 + kn + mc0);
            mreg1 = *(const uint4*)(Mp + (size_t)mrow * 2048 + kn + mc0 + 16);
        }

        float4v s0[4], s1[4];
        for (int nt = 0; nt < 4; ++nt) {
            const float4v z4 = float4v{0.f, 0.f, 0.f, 0.f};
            bf16x8 kf = *(const bf16x8*)&Ks[nt * 16 + l16][quad * 8];
            s0[nt] = MFMA16(kf, qf[0][0], z4);
            s1[nt] = MFMA16(kf, qf[1][0], z4);
            kf = *(const bf16x8*)&Ks[nt * 16 + l16][32 + quad * 8];
            s0[nt] = MFMA16(kf, qf[0][1], s0[nt]);
            s1[nt] = MFMA16(kf, qf[1][1], s1[nt]);
        }

        for (int c = 0; c < 2; ++c) {
            float4v* s = c ? s1 : s0;
            const int qrow = w * 32 + c * 16 + l16;
            float lc = l_acc[c];
            for (int nt = 0; nt < 4; ++nt) {
                float p0 = s[nt][0], p1 = s[nt][1], p2 = s[nt][2], p3 = s[nt][3];
                if (anymask) {
                    const unsigned char* mr =
                        Mp + (size_t)qrow * 2048 + kc + nt * 16 + quad * 4;
                    if (mr[0]) p0 = -1e18f;
                    if (mr[1]) p1 = -1e18f;
                    if (mr[2]) p2 = -1e18f;
                    if (mr[3]) p3 = -1e18f;
                }
                const float e0 = fast_exp2(p0), e1 = fast_exp2(p1);
                const float e2 = fast_exp2(p2), e3 = fast_exp2(p3);
                lc += (e0 + e1) + (e2 + e3);
                uint2 u;
                u.x = (unsigned int)f2bf(e0) | ((unsigned int)f2bf(e1) << 16);
                u.y = (unsigned int)f2bf(e2) | ((unsigned int)f2bf(e3) << 16);
                *(uint2*)&Pt[qrow][nt * 16 + quad * 4] = u;
            }
            l_acc[c] = lc;
        }

        for (int ks = 0; ks < 2; ++ks) {
            bf16x8 pf0 = *(const bf16x8*)&Pt[w * 32 + l16][ks * 32 + quad * 8];
            bf16x8 pf1 = *(const bf16x8*)&Pt[w * 32 + 16 + l16][ks * 32 + quad * 8];
            for (int dt = 0; dt < 4; ++dt) {
                bf16x8 vf = *(const bf16x8*)&Vt[dt * 16 + l16][ks * 32 + quad * 8];
                o[0][dt] = MFMA16(pf0, vf, o[0][dt]);
                o[1][dt] = MFMA16(pf1, vf, o[1][dt]);
            }
        }
    }

    float lfull[2];
    for (int c = 0; c < 2; ++c) {
        float l = l_acc[c];
        l += __shfl_xor(l, 16);
        l += __shfl_xor(l, 32);
        lfull[c] = l;
    }

    for (int c = 0; c < 2; ++c) {
        float inv[4];
        for (int reg = 0; reg < 4; ++reg)
            inv[reg] = 1.0f / __shfl(lfull[c], (lane & 48) | (quad * 4 + reg));
        for (int dt = 0; dt < 4; ++dt) {
            const int dcol = dt * 16 + l16;
            for (int reg = 0; reg < 4; ++reg) {
                const int ql = w * 32 + c * 16 + quad * 4 + reg;
                Ctx[((size_t)(b * 2048 + qt * 128 + ql)) * 1024 + h * 64 + dcol] =
                    f2bf(o[c][dt][reg] * inv[reg]);
            }
        }
    }
}

extern "C" void kernel_launch(void* const* d_in, const int* in_sizes, int n_in,
                              void* d_out, int out_size, void* d_ws, size_t ws_size,
                              hipStream_t stream) {
    (void)in_sizes; (void)n_in; (void)out_size;
    const float* query = (const float*)d_in[0];
    const float* key   = (const float*)d_in[1];
    const float* value = (const float*)d_in[2];
    const unsigned char* mask = (const unsigned char*)d_in[3];
    const float* Wq = (const float*)d_in[4];
    const float* bq = (const float*)d_in[5];
    const float* Wk = (const float*)d_in[6];
    const float* bk = (const float*)d_in[7];
    const float* Wv = (const float*)d_in[8];
    const float* bv = (const float*)d_in[9];
    const float* Wo = (const float*)d_in[10];
    const float* bo = (const float*)d_in[11];

    const size_t MD = (size_t)4096 * 1024;
    const size_t WD = (size_t)1024 * 1024;

    unsigned short* Qb  = (unsigned short*)d_ws;   // projected Q/K/V (bf16)
    unsigned short* Kb  = Qb + MD;
    unsigned short* Vb  = Kb + MD;
    unsigned short* qb  = Vb + MD;                 // bf16 inputs (dead after qkv)
    unsigned short* kb  = qb + MD;
    unsigned short* vb  = kb + MD;
    unsigned short* Wqb = vb + MD;
    unsigned short* Wkb = Wqb + WD;
    unsigned short* Wvb = Wkb + WD;
    unsigned short* Wob = Wvb + WD;
    unsigned short* Cb  = qb;                      // context aliases qb (dead by then)

    // split-K attention partials (f32), appended past the bf16 buffers
    float* Opart = (float*)(Wob + WD);             // 2 halves x 512 blocks x 128 x 64
    float* Lpart = Opart + (size_t)2 * 512 * 8192; // 2 halves x 512 x 128
    const size_t need = (size_t)(6 * MD + 4 * WD) * 2 +
                        ((size_t)2 * 512 * 8192 + (size_t)2 * 512 * 128) * 4;

    Cvt7 cv;
    cv.seg[0] = {query, qb, (int)MD};
    cv.seg[1] = {key,   kb, (int)MD};
    cv.seg[2] = {value, vb, (int)MD};
    cv.seg[3] = {Wq, Wqb, (int)WD};
    cv.seg[4] = {Wk, Wkb, (int)WD};
    cv.seg[5] = {Wv, Wvb, (int)WD};
    cv.seg[6] = {Wo, Wob, (int)WD};
    cvt_kernel<<<dim3(1024, 7), 256, 0, stream>>>(cv);

    // Q scale = (1/sqrt(64)) * log2(e); scores then live in log2 domain
    const float qscale = 0.125f * 1.44269504088896f;
    gemm_qkv_kernel<<<dim3(32, 8, 3), 256, 0, stream>>>(
        qb, kb, vb, Wqb, Wkb, Wvb, bq, bk, bv, Qb, Kb, Vb, qscale);

    if (ws_size >= need) {
        attn_split_kernel<<<dim3(1024), 256, 0, stream>>>(Qb, Kb, Vb, mask, Opart, Lpart);
        attn_merge_kernel<<<dim3(512), 256, 0, stream>>>(Opart, Lpart, Cb);
    } else {
        attn_kernel<<<dim3(512), 256, 0, stream>>>(Qb, Kb, Vb, mask, Cb);
    }

    gemm_out_kernel<<<dim3(64, 8), 256, 0, stream>>>(Cb, Wob, bo, (float*)d_out);
}

// Round 2
// 274.942 us; speedup vs baseline: 1.0132x; 1.0132x over previous
//
#include <hip/hip_runtime.h>
#include <hip/hip_bf16.h>

typedef __attribute__((ext_vector_type(4))) float float4v;
typedef __attribute__((ext_vector_type(8))) __bf16 bf16x8;
typedef __attribute__((ext_vector_type(4))) unsigned short ushort4v;
typedef __attribute__((ext_vector_type(8))) unsigned short ushort8v;

#define MFMA16(a, b, c) __builtin_amdgcn_mfma_f32_16x16x32_bf16(a, b, c, 0, 0, 0)

__device__ __forceinline__ unsigned short f2bf(float f) {
    return __builtin_bit_cast(unsigned short, (__bf16)f);
}

// 2^x via native v_exp_f32 (args bounded above by ~13; may be -1e18 -> 0)
__device__ __forceinline__ float fast_exp2(float x) {
#if __has_builtin(__builtin_amdgcn_exp2f)
    return __builtin_amdgcn_exp2f(x);
#else
    return exp2f(x);
#endif
}

// async global->LDS, 16B per lane; lds dest must be wave-uniform base + lane*16
__device__ __forceinline__ void gl_lds16(const unsigned short* g, unsigned short* l) {
    __builtin_amdgcn_global_load_lds(
        (const __attribute__((address_space(1))) void*)g,
        (__attribute__((address_space(3))) void*)l, 16, 0, 0);
}

// ---------------------------------------------------------------------------
// fp32 -> bf16 convert, 7 segments in one launch. 8 elements/thread.
// grid (512, 7): 512*256*8 = 1M elements/sweep -> WD segs in 1 sweep, MD in 4.
// ---------------------------------------------------------------------------
struct CvtSeg { const float* s; unsigned short* d; int n; };
struct Cvt7 { CvtSeg seg[7]; };

__global__ __launch_bounds__(256) void cvt_kernel(Cvt7 a) {
    const CvtSeg c = a.seg[blockIdx.y];
    const int stride = gridDim.x * 256 * 8;
    for (int i = (blockIdx.x * 256 + threadIdx.x) * 8; i < c.n; i += stride) {
        float4v v0 = *(const float4v*)(c.s + i);
        float4v v1 = *(const float4v*)(c.s + i + 4);
        ushort8v u;
        u[0] = f2bf(v0.x); u[1] = f2bf(v0.y); u[2] = f2bf(v0.z); u[3] = f2bf(v0.w);
        u[4] = f2bf(v1.x); u[5] = f2bf(v1.y); u[6] = f2bf(v1.z); u[7] = f2bf(v1.w);
        *(ushort8v*)(c.d + i) = u;
    }
}

// ---------------------------------------------------------------------------
// 128x128-tile GEMM body (QKV projections): C = (A W^T + bias) * scale, bf16.
// ---------------------------------------------------------------------------
__device__ __forceinline__ void gemm128_body(const unsigned short* __restrict__ A,
                                             const unsigned short* __restrict__ W,
                                             const float* __restrict__ bias,
                                             unsigned short* __restrict__ Cout,
                                             int N, int K, float scale,
                                             unsigned short* As, unsigned short* Ws,
                                             int m0, int n0) {
    const int t = threadIdx.x;
    const int w = t >> 6, lane = t & 63;
    const int quad = lane >> 4, l16 = lane & 15;
    const int wm = (w >> 1) * 64, wn = (w & 1) * 64;

    float4v acc[4][4];
    for (int i = 0; i < 4; ++i)
        for (int j = 0; j < 4; ++j) acc[i][j] = float4v{0.f, 0.f, 0.f, 0.f};

    const int srow = lane >> 3;
    const int scol = (lane & 7) * 8;

    for (int k0 = 0; k0 < K; k0 += 64) {
        __syncthreads();
        for (int i = 0; i < 4; ++i) {
            const int c = w * 4 + i;
            gl_lds16(A + (size_t)(m0 + c * 8 + srow) * K + k0 + scol,
                     &As[c * 512 + lane * 8]);
            gl_lds16(W + (size_t)(n0 + c * 8 + srow) * K + k0 + scol,
                     &Ws[c * 512 + lane * 8]);
        }
        __syncthreads();
        for (int ks = 0; ks < 2; ++ks) {
            bf16x8 af[4], wf[4];
            for (int i = 0; i < 4; ++i)
                af[i] = *(const bf16x8*)&As[(wm + i * 16 + l16) * 64 + ks * 32 + quad * 8];
            for (int i = 0; i < 4; ++i)
                wf[i] = *(const bf16x8*)&Ws[(wn + i * 16 + l16) * 64 + ks * 32 + quad * 8];
            for (int mi = 0; mi < 4; ++mi)
                for (int ni = 0; ni < 4; ++ni)
                    acc[mi][ni] = MFMA16(af[mi], wf[ni], acc[mi][ni]);
        }
    }

    for (int mi = 0; mi < 4; ++mi)
        for (int ni = 0; ni < 4; ++ni) {
            const int col = n0 + wn + ni * 16 + l16;
            const float bv = bias[col];
            for (int reg = 0; reg < 4; ++reg) {
                const int row = m0 + wm + mi * 16 + quad * 4 + reg;
                Cout[(size_t)row * N + col] = f2bf((acc[mi][ni][reg] + bv) * scale);
            }
        }
}

// 1-D grid 768 with XCD-chunked swizzle (768 = 8 * 96, bijective):
// XCD k gets 3 contiguous (n-panel, z) combos x 32 m-tiles -> W panel L2-reuse.
__global__ __launch_bounds__(256) void gemm_qkv_kernel(
    const unsigned short* qa, const unsigned short* ka, const unsigned short* va,
    const unsigned short* Wqb, const unsigned short* Wkb, const unsigned short* Wvb,
    const float* bq, const float* bk, const float* bv,
    unsigned short* Qb, unsigned short* Kb, unsigned short* Vb, float qscale) {
    __shared__ unsigned short As[128 * 64];
    __shared__ unsigned short Ws[128 * 64];
    const int id = blockIdx.x;
    const int work = (id & 7) * 96 + (id >> 3);
    const int x = work & 31;        // m-tile
    const int combo = work >> 5;    // 0..23
    const int y = combo & 7;        // n-tile
    const int z = combo >> 3;       // 0..2 (q/k/v)
    const unsigned short* A = z == 0 ? qa : (z == 1 ? ka : va);
    const unsigned short* W = z == 0 ? Wqb : (z == 1 ? Wkb : Wvb);
    const float* bias = z == 0 ? bq : (z == 1 ? bk : bv);
    unsigned short* C = z == 0 ? Qb : (z == 1 ? Kb : Vb);
    gemm128_body(A, W, bias, C, 1024, 1024, z == 0 ? qscale : 1.0f, As, Ws,
                 x * 128, y * 128);
}

// ---------------------------------------------------------------------------
// Output projection GEMM, fp32 out. 64x64 tiles -> grid 1024 = 4 blocks/CU
// (old 64x128 at 512 blocks = 2/CU was the slowest dispatch, ~140 TF).
// XCD-chunked swizzle (1024 = 8 * 128).
// ---------------------------------------------------------------------------
__global__ __launch_bounds__(256) void gemm_out_kernel(const unsigned short* __restrict__ A,
                                                       const unsigned short* __restrict__ W,
                                                       const float* __restrict__ bias,
                                                       float* __restrict__ Cout) {
    __shared__ unsigned short As[64 * 64];
    __shared__ unsigned short Ws[64 * 64];
    const int N = 1024, K = 1024;
    const int t = threadIdx.x;
    const int w = t >> 6, lane = t & 63;
    const int quad = lane >> 4, l16 = lane & 15;
    const int id = blockIdx.x;
    const int work = (id & 7) * 128 + (id >> 3);
    const int m0 = (work & 63) * 64;   // 64 m-tiles
    const int n0 = (work >> 6) * 64;   // 16 n-tiles
    const int wm = (w >> 1) * 32, wn = (w & 1) * 32;

    float4v acc[2][2];
    for (int i = 0; i < 2; ++i)
        for (int j = 0; j < 2; ++j) acc[i][j] = float4v{0.f, 0.f, 0.f, 0.f};

    const int srow = lane >> 3;
    const int scol = (lane & 7) * 8;

    for (int k0 = 0; k0 < K; k0 += 64) {
        __syncthreads();
        for (int i = 0; i < 2; ++i) {
            const int c = w * 2 + i;
            gl_lds16(A + (size_t)(m0 + c * 8 + srow) * K + k0 + scol,
                     &As[c * 512 + lane * 8]);
            gl_lds16(W + (size_t)(n0 + c * 8 + srow) * K + k0 + scol,
                     &Ws[c * 512 + lane * 8]);
        }
        __syncthreads();
        for (int ks = 0; ks < 2; ++ks) {
            bf16x8 af[2], wf[2];
            for (int i = 0; i < 2; ++i)
                af[i] = *(const bf16x8*)&As[(wm + i * 16 + l16) * 64 + ks * 32 + quad * 8];
            for (int i = 0; i < 2; ++i)
                wf[i] = *(const bf16x8*)&Ws[(wn + i * 16 + l16) * 64 + ks * 32 + quad * 8];
            for (int mi = 0; mi < 2; ++mi)
                for (int ni = 0; ni < 2; ++ni)
                    acc[mi][ni] = MFMA16(af[mi], wf[ni], acc[mi][ni]);
        }
    }

    for (int mi = 0; mi < 2; ++mi)
        for (int ni = 0; ni < 2; ++ni) {
            const int col = n0 + wn + ni * 16 + l16;
            const float bv = bias[col];
            for (int reg = 0; reg < 4; ++reg) {
                const int row = m0 + wm + mi * 16 + quad * 4 + reg;
                Cout[(size_t)row * N + col] = acc[mi][ni][reg] + bv;
            }
        }
}

// ---------------------------------------------------------------------------
// Flash attention, S^T formulation, 128 q-rows/block (32 q per wave): each
// K/V fragment read serves 2 q-groups, halving the dominant LDS terms.
// Lane packs 4 consecutive keys -> ds_write_b64 directly in A-layout Pt[q][k].
// l = per-lane scalar accumulators (q = l16 per group), shfl-reduced once.
// Grid: 512 blocks (bh fastest for XCD L2 locality).
// (Split-K variant tried in R1: occupancy 2x but zero gain -> not
//  occupancy-bound; reverted to this version.)
// ---------------------------------------------------------------------------
__global__ __launch_bounds__(256) void attn_kernel(const unsigned short* __restrict__ Q,
                                                   const unsigned short* __restrict__ Kg,
                                                   const unsigned short* __restrict__ Vg,
                                                   const unsigned char* __restrict__ mask,
                                                   unsigned short* __restrict__ Ctx) {
    const int bid = blockIdx.x;
    const int bh = bid & 31;   // fastest -> same-XCD blocks share (b,h) K/V
    const int qt = bid >> 5;   // 0..15 (128-row q tile)
    const int b = bh >> 4, h = bh & 15;
    const int t = threadIdx.x, w = t >> 6, lane = t & 63;
    const int quad = lane >> 4, l16 = lane & 15;

    __shared__ unsigned short Pt[128][72];  // Q at start; then P in A-layout [q][key]
    __shared__ unsigned short Ks[64][72];
    __shared__ unsigned short Vt[64][72];   // transposed V: Vt[d][k]

    const unsigned short* Qp = Q + ((size_t)(b * 2048 + qt * 128)) * 1024 + h * 64;
    const unsigned short* Kp = Kg + ((size_t)b * 2048) * 1024 + h * 64;
    const unsigned short* Vp = Vg + ((size_t)b * 2048) * 1024 + h * 64;
    const unsigned char* Mp = mask + (size_t)(b * 2048 + qt * 128) * 2048;

    for (int p = 0; p < 4; ++p) {  // Q tile 128x64 -> Pt
        const int idx = t + p * 256;
        const int r = idx >> 3, c8 = (idx & 7) * 8;
        *(uint4*)&Pt[r][c8] = *(const uint4*)(Qp + (size_t)r * 1024 + c8);
    }
    __syncthreads();
    // qf[c] = B-operand fragment for q-group c (q = w*32 + c*16 + l16)
    bf16x8 qf[2][2];
    for (int c = 0; c < 2; ++c)
        for (int ks = 0; ks < 2; ++ks)
            qf[c][ks] = *(const bf16x8*)&Pt[w * 32 + c * 16 + l16][ks * 32 + quad * 8];

    float4v o[2][4];  // [q-chunk][d-tile]
    for (int c = 0; c < 2; ++c)
        for (int i = 0; i < 4; ++i) o[c][i] = float4v{0.f, 0.f, 0.f, 0.f};
    float l_acc[2] = {0.f, 0.f};  // per-lane partial row-sum for q-group c

    const int sr = t >> 3, sc8 = (t & 7) * 8;          // K staging map
    const int vkk = (t & 31) * 2, vd0 = (t >> 5) * 8;  // V staging map
    const int mrow = w * 32 + (lane >> 1);             // mask probe: 32 rows x 64 B
    const int mc0 = (lane & 1) * 32;

    uint4 kreg0, kreg1, vreg0, vreg1, mreg0, mreg1;
    {
        kreg0 = *(const uint4*)(Kp + (size_t)sr * 1024 + sc8);
        kreg1 = *(const uint4*)(Kp + (size_t)(sr + 32) * 1024 + sc8);
        vreg0 = *(const uint4*)(Vp + (size_t)vkk * 1024 + vd0);
        vreg1 = *(const uint4*)(Vp + (size_t)(vkk + 1) * 1024 + vd0);
        mreg0 = *(const uint4*)(Mp + (size_t)mrow * 2048 + mc0);
        mreg1 = *(const uint4*)(Mp + (size_t)mrow * 2048 + mc0 + 16);
    }

    for (int kc = 0; kc < 2048; kc += 64) {
        __syncthreads();  // prev iter's Ks/Vt readers done
        *(uint4*)&Ks[sr][sc8] = kreg0;
        *(uint4*)&Ks[sr + 32][sc8] = kreg1;
        {
            const unsigned short* pa = (const unsigned short*)&vreg0;
            const unsigned short* pb = (const unsigned short*)&vreg1;
            for (int j = 0; j < 8; ++j)
                *(unsigned int*)&Vt[vd0 + j][vkk] =
                    (unsigned int)pa[j] | ((unsigned int)pb[j] << 16);
        }
        const unsigned int mor = mreg0.x | mreg0.y | mreg0.z | mreg0.w |
                                 mreg1.x | mreg1.y | mreg1.z | mreg1.w;
        const bool anymask = __any(mor != 0);
        __syncthreads();  // staged data visible

        const int kn = kc + 64;
        if (kn < 2048) {  // prefetch next tile
            kreg0 = *(const uint4*)(Kp + (size_t)(kn + sr) * 1024 + sc8);
            kreg1 = *(const uint4*)(Kp + (size_t)(kn + sr + 32) * 1024 + sc8);
            vreg0 = *(const uint4*)(Vp + (size_t)(kn + vkk) * 1024 + vd0);
            vreg1 = *(const uint4*)(Vp + (size_t)(kn + vkk + 1) * 1024 + vd0);
            mreg0 = *(const uint4*)(Mp + (size_t)mrow * 2048 + kn + mc0);
            mreg1 = *(const uint4*)(Mp + (size_t)mrow * 2048 + kn + mc0 + 16);
        }

        // S^T = K Q^T for both q-groups; each kf read feeds 2 MFMAs
        float4v s0[4], s1[4];
        for (int nt = 0; nt < 4; ++nt) {
            const float4v z4 = float4v{0.f, 0.f, 0.f, 0.f};
            bf16x8 kf = *(const bf16x8*)&Ks[nt * 16 + l16][quad * 8];
            s0[nt] = MFMA16(kf, qf[0][0], z4);
            s1[nt] = MFMA16(kf, qf[1][0], z4);
            kf = *(const bf16x8*)&Ks[nt * 16 + l16][32 + quad * 8];
            s0[nt] = MFMA16(kf, qf[0][1], s0[nt]);
            s1[nt] = MFMA16(kf, qf[1][1], s1[nt]);
        }

        // exp2 + pack 4 consecutive keys -> one b64 store in A-layout
        for (int c = 0; c < 2; ++c) {
            float4v* s = c ? s1 : s0;
            const int qrow = w * 32 + c * 16 + l16;  // wave-private Pt row
            float lc = l_acc[c];
            for (int nt = 0; nt < 4; ++nt) {
                float p0 = s[nt][0], p1 = s[nt][1], p2 = s[nt][2], p3 = s[nt][3];
                if (anymask) {  // rare slow path: scalar byte re-read
                    const unsigned char* mr =
                        Mp + (size_t)qrow * 2048 + kc + nt * 16 + quad * 4;
                    if (mr[0]) p0 = -1e18f;
                    if (mr[1]) p1 = -1e18f;
                    if (mr[2]) p2 = -1e18f;
                    if (mr[3]) p3 = -1e18f;
                }
                const float e0 = fast_exp2(p0), e1 = fast_exp2(p1);
                const float e2 = fast_exp2(p2), e3 = fast_exp2(p3);
                lc += (e0 + e1) + (e2 + e3);
                uint2 u;
                u.x = (unsigned int)f2bf(e0) | ((unsigned int)f2bf(e1) << 16);
                u.y = (unsigned int)f2bf(e2) | ((unsigned int)f2bf(e3) << 16);
                *(uint2*)&Pt[qrow][nt * 16 + quad * 4] = u;
            }
            l_acc[c] = lc;
        }

        // O += P V ; each vf read feeds 2 MFMAs (both q-chunks)
        for (int ks = 0; ks < 2; ++ks) {
            bf16x8 pf0 = *(const bf16x8*)&Pt[w * 32 + l16][ks * 32 + quad * 8];
            bf16x8 pf1 = *(const bf16x8*)&Pt[w * 32 + 16 + l16][ks * 32 + quad * 8];
            for (int dt = 0; dt < 4; ++dt) {
                bf16x8 vf = *(const bf16x8*)&Vt[dt * 16 + l16][ks * 32 + quad * 8];
                o[0][dt] = MFMA16(pf0, vf, o[0][dt]);
                o[1][dt] = MFMA16(pf1, vf, o[1][dt]);
            }
        }
    }

    // reduce l over quads (uniform across quads after xor 16/32), per q-group
    float lfull[2];
    for (int c = 0; c < 2; ++c) {
        float l = l_acc[c];
        l += __shfl_xor(l, 16);
        l += __shfl_xor(l, 32);
        lfull[c] = l;
    }

    for (int c = 0; c < 2; ++c) {
        float inv[4];
        for (int reg = 0; reg < 4; ++reg)
            inv[reg] = 1.0f / __shfl(lfull[c], (lane & 48) | (quad * 4 + reg));
        for (int dt = 0; dt < 4; ++dt) {
            const int dcol = dt * 16 + l16;
            for (int reg = 0; reg < 4; ++reg) {
                const int ql = w * 32 + c * 16 + quad * 4 + reg;
                Ctx[((size_t)(b * 2048 + qt * 128 + ql)) * 1024 + h * 64 + dcol] =
                    f2bf(o[c][dt][reg] * inv[reg]);
            }
        }
    }
}

extern "C" void kernel_launch(void* const* d_in, const int* in_sizes, int n_in,
                              void* d_out, int out_size, void* d_ws, size_t ws_size,
                              hipStream_t stream) {
    (void)in_sizes; (void)n_in; (void)out_size; (void)ws_size;
    const float* query = (const float*)d_in[0];
    const float* key   = (const float*)d_in[1];
    const float* value = (const float*)d_in[2];
    const unsigned char* mask = (const unsigned char*)d_in[3];
    const float* Wq = (const float*)d_in[4];
    const float* bq = (const float*)d_in[5];
    const float* Wk = (const float*)d_in[6];
    const float* bk = (const float*)d_in[7];
    const float* Wv = (const float*)d_in[8];
    const float* bv = (const float*)d_in[9];
    const float* Wo = (const float*)d_in[10];
    const float* bo = (const float*)d_in[11];

    const size_t MD = (size_t)4096 * 1024;
    const size_t WD = (size_t)1024 * 1024;

    unsigned short* Qb  = (unsigned short*)d_ws;   // projected Q/K/V (bf16)
    unsigned short* Kb  = Qb + MD;
    unsigned short* Vb  = Kb + MD;
    unsigned short* qb  = Vb + MD;                 // bf16 inputs (dead after qkv)
    unsigned short* kb  = qb + MD;
    unsigned short* vb  = kb + MD;
    unsigned short* Wqb = vb + MD;
    unsigned short* Wkb = Wqb + WD;
    unsigned short* Wvb = Wkb + WD;
    unsigned short* Wob = Wvb + WD;
    unsigned short* Cb  = qb;                      // context aliases qb (dead by then)

    Cvt7 cv;
    cv.seg[0] = {query, qb, (int)MD};
    cv.seg[1] = {key,   kb, (int)MD};
    cv.seg[2] = {value, vb, (int)MD};
    cv.seg[3] = {Wq, Wqb, (int)WD};
    cv.seg[4] = {Wk, Wkb, (int)WD};
    cv.seg[5] = {Wv, Wvb, (int)WD};
    cv.seg[6] = {Wo, Wob, (int)WD};
    cvt_kernel<<<dim3(512, 7), 256, 0, stream>>>(cv);

    // Q scale = (1/sqrt(64)) * log2(e); scores then live in log2 domain
    const float qscale = 0.125f * 1.44269504088896f;
    gemm_qkv_kernel<<<dim3(768), 256, 0, stream>>>(
        qb, kb, vb, Wqb, Wkb, Wvb, bq, bk, bv, Qb, Kb, Vb, qscale);

    attn_kernel<<<dim3(512), 256, 0, stream>>>(Qb, Kb, Vb, mask, Cb);

    gemm_out_kernel<<<dim3(1024), 256, 0, stream>>>(Cb, Wob, bo, (float*)d_out);
}